// Round 17
// baseline (58.177 us; speedup 1.0000x reference)
//
#include <hip/hip_runtime.h>
#include <hip/hip_bf16.h>

#define B_ 8
#define T_ 2048
#define V_ 256
#define D_ 512
#define LEFT_ 16

typedef float f32x4 __attribute__((ext_vector_type(4)));
typedef short bf16x8 __attribute__((ext_vector_type(8)));
union FragU { unsigned u[4]; bf16x8 v; };

__device__ __forceinline__ unsigned pack_bf2(float a, float b) {
    __hip_bfloat162 h = __float22bfloat162_rn(make_float2(a, b));
    union { __hip_bfloat162 h; unsigned u; } c; c.h = h; return c.u;
}

// Wave-autonomous: each wave owns 4 tokens; no LDS, no barriers, no cross-wave deps.
// Scores: MFMA 16x16x32, A = window rows (j = t, 16+t; junk rows clamped),
//   B cols 0-3 = the 4 tokens' enc (cols 4-15 junk, never read).
//   Maps verified R10-R15: A/B k = 4q+(e&3)+16*(e>>2); D col = lane&15, row = 4q+r.
// Softmax: R10's masked band code verbatim (valid for cols t<4).
// Phase B: R8's dense C-row weighted sum; p pulled via compile-time __shfl from
//   D-fragment lanes: p(tk, sl=i-tk) lives in lane ((i&15)>>2)*16 + tk, reg p{i>>4}[i&3].
__global__ __launch_bounds__(256)
void attn_cell_kernel(const int* __restrict__ symbols,
                      const float* __restrict__ encodings,
                      const float* __restrict__ M,
                      const float* __restrict__ C,
                      float* __restrict__ out,      // (B,T,1024)
                      float* __restrict__ p_out) {  // (B,T,16)
    const int tid  = threadIdx.x;
    const int lane = tid & 63;
    const int w    = tid >> 6;
    const int q    = lane >> 4;
    const int t    = lane & 15;

    const int blk = blockIdx.x;
    const int b   = blk >> 7;                       // 128 blocks per batch row
    const int tb  = (blk & 127) * 16 + w * 4;       // wave's first token
    const int* symrow = symbols + b * T_;
    const size_t rowbase = (size_t)b * T_ + tb;
    const int dof = lane * 8;

    // window symbols (19 rows) -> SGPRs for phase B (constant-indexed only)
    int syms[19];
    #pragma unroll
    for (int i = 0; i < 19; ++i) {
        int pos = tb - (LEFT_ - 1) + i;
        pos = max(pos, 0);
        syms[i] = __builtin_amdgcn_readfirstlane(symrow[pos]);
    }

    // ---- enc passthrough: dense, 1 KB per instruction ----
    #pragma unroll
    for (int tk = 0; tk < 4; ++tk) {
        const float* e = encodings + (rowbase + tk) * D_ + dof;
        const float4 x0 = *(const float4*)e;
        const float4 x1 = *(const float4*)(e + 4);
        float* o = out + (rowbase + tk) * 1024 + D_ + dof;
        *(float4*)o       = x0;
        *(float4*)(o + 4) = x1;
    }

    // per-lane A-row symbols (vector loads, L1-hot; R10 pattern)
    int pos0 = tb - (LEFT_ - 1) + t;  pos0 = max(pos0, 0);
    int pos1 = tb + 1 + min(t, 2);                   // rows 16..18, junk clamped
    const int sym0 = symrow[pos0];
    const int sym1 = symrow[pos1];

    // ---- phase A: 32 MFMAs over K=512 ----
    f32x4 acc0 = {0.f, 0.f, 0.f, 0.f}, acc1 = {0.f, 0.f, 0.f, 0.f};
    {
        const float* eb  = encodings + (rowbase + (t & 3)) * D_;   // cols>=4 duplicate
        const float* ma0 = M + (size_t)sym0 * D_;
        const float* ma1 = M + (size_t)sym1 * D_;
        #pragma unroll
        for (int ks = 0; ks < 16; ++ks) {
            const int k0 = ks * 32 + 4 * q;
            const float4 e0 = *(const float4*)(eb + k0);
            const float4 e1 = *(const float4*)(eb + k0 + 16);
            FragU bf;
            bf.u[0] = pack_bf2(e0.x, e0.y); bf.u[1] = pack_bf2(e0.z, e0.w);
            bf.u[2] = pack_bf2(e1.x, e1.y); bf.u[3] = pack_bf2(e1.z, e1.w);
            const float4 m00 = *(const float4*)(ma0 + k0);
            const float4 m01 = *(const float4*)(ma0 + k0 + 16);
            FragU a0;
            a0.u[0] = pack_bf2(m00.x, m00.y); a0.u[1] = pack_bf2(m00.z, m00.w);
            a0.u[2] = pack_bf2(m01.x, m01.y); a0.u[3] = pack_bf2(m01.z, m01.w);
            const float4 m10 = *(const float4*)(ma1 + k0);
            const float4 m11 = *(const float4*)(ma1 + k0 + 16);
            FragU a1;
            a1.u[0] = pack_bf2(m10.x, m10.y); a1.u[1] = pack_bf2(m10.z, m10.w);
            a1.u[2] = pack_bf2(m11.x, m11.y); a1.u[3] = pack_bf2(m11.z, m11.w);
            acc0 = __builtin_amdgcn_mfma_f32_16x16x32_bf16(a0.v, bf.v, acc0, 0, 0, 0);
            acc1 = __builtin_amdgcn_mfma_f32_16x16x32_bf16(a1.v, bf.v, acc1, 0, 0, 0);
        }
    }

    // ---- masked band softmax (R10 verbatim; valid in cols t<4) ----
    float p0[4], p1[4];
    {
        float mx = -3.0e38f;
        #pragma unroll
        for (int r = 0; r < 4; ++r) {
            if ((unsigned)(4 * q + r - t) < 16u)      mx = fmaxf(mx, acc0[r]);
            if ((unsigned)(4 * q + r + 16 - t) < 16u) mx = fmaxf(mx, acc1[r]);
        }
        mx = fmaxf(mx, __shfl_xor(mx, 16));
        mx = fmaxf(mx, __shfl_xor(mx, 32));
        float sum = 0.f;
        #pragma unroll
        for (int r = 0; r < 4; ++r) {
            const bool m0 = (unsigned)(4 * q + r - t) < 16u;
            const bool m1 = (unsigned)(4 * q + r + 16 - t) < 16u;
            p0[r] = m0 ? __expf(acc0[r] - mx) : 0.f;
            p1[r] = m1 ? __expf(acc1[r] - mx) : 0.f;
            sum += p0[r] + p1[r];
        }
        sum += __shfl_xor(sum, 16);
        sum += __shfl_xor(sum, 32);
        const float inv = 1.f / sum;
        #pragma unroll
        for (int r = 0; r < 4; ++r) { p0[r] *= inv; p1[r] *= inv; }
    }

    // ---- p_out: lanes t<4 own token t (R10 pattern) ----
    if (t < 4) {
        #pragma unroll
        for (int r = 0; r < 4; ++r) {
            const int j0 = 4 * q + r;
            if ((unsigned)(j0 - t) < 16u)
                p_out[(rowbase + t) * 16 + (j0 - t)] = p0[r];
            else
                p_out[(rowbase + t) * 16 + (j0 + 16 - t)] = p1[r];
        }
    }

    // ---- phase B: dense C-row weighted sum (R8 pattern), p via static shfl ----
    float4 a0[4], a1[4];
    #pragma unroll
    for (int tk = 0; tk < 4; ++tk) {
        a0[tk] = make_float4(0.f, 0.f, 0.f, 0.f);
        a1[tk] = make_float4(0.f, 0.f, 0.f, 0.f);
    }
    #pragma unroll
    for (int i = 0; i < 19; ++i) {
        const float* cr = C + (size_t)syms[i] * D_ + dof;
        const float4 c0 = *(const float4*)cr;
        const float4 c1 = *(const float4*)(cr + 4);
        #pragma unroll
        for (int tk = 0; tk < 4; ++tk) {
            const int sl = i - tk;
            if (sl >= 0 && sl < 16) {
                const int src = ((i & 15) >> 2) * 16 + tk;     // compile-time
                const float pb = (i >= 16) ? __shfl(p1[i & 3], src)
                                           : __shfl(p0[i & 3], src);
                a0[tk].x += pb * c0.x; a0[tk].y += pb * c0.y;
                a0[tk].z += pb * c0.z; a0[tk].w += pb * c0.w;
                a1[tk].x += pb * c1.x; a1[tk].y += pb * c1.y;
                a1[tk].z += pb * c1.z; a1[tk].w += pb * c1.w;
            }
        }
    }

    // ---- dense stores: 1 KB per instruction ----
    #pragma unroll
    for (int tk = 0; tk < 4; ++tk) {
        float* ob = out + (rowbase + tk) * 1024 + dof;
        *(float4*)ob       = a0[tk];
        *(float4*)(ob + 4) = a1[tk];
    }
}

extern "C" void kernel_launch(void* const* d_in, const int* in_sizes, int n_in,
                              void* d_out, int out_size, void* d_ws, size_t ws_size,
                              hipStream_t stream) {
    const int*   symbols   = (const int*)d_in[0];
    const float* encodings = (const float*)d_in[1];
    const float* M         = (const float*)d_in[2];
    const float* C         = (const float*)d_in[3];
    float* out   = (float*)d_out;
    float* p_out = out + (size_t)B_ * T_ * 1024;   // concat order: output, then p

    dim3 grid(B_ * (T_ / 16));                     // 1024 blocks x 256 threads
    attn_cell_kernel<<<grid, 256, 0, stream>>>(symbols, encodings, M, C, out, p_out);
}

// Round 18
// 33.329 us; speedup vs baseline: 1.7456x; 1.7456x over previous
//
#include <hip/hip_runtime.h>
#include <hip/hip_bf16.h>

#define B_ 8
#define T_ 2048
#define V_ 256
#define D_ 512
#define LEFT_ 16

typedef float f32x4 __attribute__((ext_vector_type(4)));
typedef short bf16x8 __attribute__((ext_vector_type(8)));
typedef unsigned long long u64;
union FragU { unsigned u[4]; u64 ull[2]; bf16x8 v; };

__device__ __forceinline__ unsigned pack_bf2(float a, float b) {
    __hip_bfloat162 h = __float22bfloat162_rn(make_float2(a, b));
    union { __hip_bfloat162 h; unsigned u; } c; c.h = h; return c.u;
}

// R15 structure (one barrier, no operand LDS, C prefetched to regs) with the
// __syncthreads() replaced by an lgkmcnt-only barrier: enc passthrough stores and
// any in-flight global loads are NOT drained at the barrier (HK/T3-T4 pattern).
// Only the spart ds_writes need cross-wave visibility -> s_waitcnt lgkmcnt(0).
__global__ __launch_bounds__(512)
void attn_cell_kernel(const int* __restrict__ symbols,
                      const float* __restrict__ encodings,
                      const float* __restrict__ M,
                      const float* __restrict__ C,
                      float* __restrict__ out,      // (B,T,1024)
                      float* __restrict__ p_out) {  // (B,T,16)
    __shared__ __align__(16) float sp[8 * 16 * 36];            // 18432 B

    const int tid  = threadIdx.x;
    const int lane = tid & 63;
    const int w    = tid >> 6;      // 0..7
    const int q    = lane >> 4;     // 0..3
    const int t    = lane & 15;

    const int blk = blockIdx.x;
    const int b   = blk >> 7;
    const int t0  = (blk & 127) * 16;
    const int* symrow = symbols + b * T_;
    const size_t rowbase = (size_t)b * T_ + t0;

    // phase-A symbols: rows j = t and t+16
    int sa[2];
    #pragma unroll
    for (int g = 0; g < 2; ++g) {
        int pos = t0 + t + 16 * g - (LEFT_ - 1);
        pos = max(pos, 0); pos = min(pos, T_ - 1);
        sa[g] = symrow[pos];
    }
    // phase-B symbols: k-elems j(e) = 4q + (e&3) + 16*(e>>2)  (R10-verified map)
    int sb[8];
    #pragma unroll
    for (int e = 0; e < 8; ++e) {
        const int j = 4 * q + (e & 3) + 16 * (e >> 2);
        int pos = t0 + j - (LEFT_ - 1);
        pos = max(pos, 0); pos = min(pos, T_ - 1);
        sb[e] = symrow[pos];
    }

    // ---- enc load, fused exact-f32 passthrough, pack B-fragments ----
    FragU bf[2];
    {
        const float* ebase = encodings + (rowbase + t) * D_;
        float* obase = out + (rowbase + t) * 1024 + D_;
        #pragma unroll
        for (int kc = 0; kc < 2; ++kc) {
            const int d0 = 64 * w + 32 * kc + 4 * q;
            const float4 e0 = *(const float4*)(ebase + d0);
            const float4 e1 = *(const float4*)(ebase + d0 + 16);
            *(float4*)(obase + d0)      = e0;
            *(float4*)(obase + d0 + 16) = e1;
            bf[kc].u[0] = pack_bf2(e0.x, e0.y); bf[kc].u[1] = pack_bf2(e0.z, e0.w);
            bf[kc].u[2] = pack_bf2(e1.x, e1.y); bf[kc].u[3] = pack_bf2(e1.z, e1.w);
        }
    }

    // ---- prefetch phase-B C fragments from L2 into packed bf16 regs ----
    FragU afc[4];
    #pragma unroll
    for (int m = 0; m < 4; ++m) {
        const int dA = (w * 4 + m) * 16 + t;
        float c[8];
        #pragma unroll
        for (int e = 0; e < 8; ++e)
            c[e] = C[(size_t)sb[e] * D_ + dA];
        afc[m].u[0] = pack_bf2(c[0], c[1]); afc[m].u[1] = pack_bf2(c[2], c[3]);
        afc[m].u[2] = pack_bf2(c[4], c[5]); afc[m].u[3] = pack_bf2(c[6], c[7]);
    }

    // ---- phase A: MFMA partials, M fragments straight from L2 (R10-verified) ----
    f32x4 acc0 = {0.f, 0.f, 0.f, 0.f}, acc1 = {0.f, 0.f, 0.f, 0.f};
    #pragma unroll
    for (int kc = 0; kc < 2; ++kc) {
        const int k0 = 64 * w + 32 * kc + 4 * q;
        {
            const float* ma = M + (size_t)sa[0] * D_ + k0;
            const float4 x0 = *(const float4*)ma;
            const float4 x1 = *(const float4*)(ma + 16);
            FragU af;
            af.u[0] = pack_bf2(x0.x, x0.y); af.u[1] = pack_bf2(x0.z, x0.w);
            af.u[2] = pack_bf2(x1.x, x1.y); af.u[3] = pack_bf2(x1.z, x1.w);
            acc0 = __builtin_amdgcn_mfma_f32_16x16x32_bf16(af.v, bf[kc].v, acc0, 0, 0, 0);
        }
        {
            const float* ma = M + (size_t)sa[1] * D_ + k0;
            const float4 x0 = *(const float4*)ma;
            const float4 x1 = *(const float4*)(ma + 16);
            FragU af;
            af.u[0] = pack_bf2(x0.x, x0.y); af.u[1] = pack_bf2(x0.z, x0.w);
            af.u[2] = pack_bf2(x1.x, x1.y); af.u[3] = pack_bf2(x1.z, x1.w);
            acc1 = __builtin_amdgcn_mfma_f32_16x16x32_bf16(af.v, bf[kc].v, acc1, 0, 0, 0);
        }
    }
    *(f32x4*)&sp[(w * 16 + t) * 36 + 4 * q]      = acc0;  // j = 4q+r
    *(f32x4*)&sp[(w * 16 + t) * 36 + 16 + 4 * q] = acc1;  // j = 16+4q+r

    // ---- barrier WITHOUT vmcnt drain: only LDS (spart) needs visibility ----
    asm volatile("s_waitcnt lgkmcnt(0)" ::: "memory");
    __builtin_amdgcn_s_barrier();
    __builtin_amdgcn_sched_barrier(0);

    // ---- reduce 8 slices; masked softmax; in-lane p handoff (verified) ----
    FragU pf;
    {
        f32x4 s0 = *(const f32x4*)&sp[t * 36 + 4 * q];
        f32x4 s1 = *(const f32x4*)&sp[t * 36 + 16 + 4 * q];
        #pragma unroll
        for (int w2 = 1; w2 < 8; ++w2) {
            s0 += *(const f32x4*)&sp[(w2 * 16 + t) * 36 + 4 * q];
            s1 += *(const f32x4*)&sp[(w2 * 16 + t) * 36 + 16 + 4 * q];
        }
        float mx = -3.0e38f;
        #pragma unroll
        for (int r = 0; r < 4; ++r) {
            if ((unsigned)(4 * q + r - t) < 16u)      mx = fmaxf(mx, s0[r]);
            if ((unsigned)(4 * q + r + 16 - t) < 16u) mx = fmaxf(mx, s1[r]);
        }
        mx = fmaxf(mx, __shfl_xor(mx, 16));
        mx = fmaxf(mx, __shfl_xor(mx, 32));
        float p0[4], p1[4];
        float sum = 0.f;
        #pragma unroll
        for (int r = 0; r < 4; ++r) {
            const bool m0 = (unsigned)(4 * q + r - t) < 16u;
            const bool m1 = (unsigned)(4 * q + r + 16 - t) < 16u;
            p0[r] = m0 ? __expf(s0[r] - mx) : 0.f;
            p1[r] = m1 ? __expf(s1[r] - mx) : 0.f;
            sum += p0[r] + p1[r];
        }
        sum += __shfl_xor(sum, 16);
        sum += __shfl_xor(sum, 32);
        const float inv = 1.f / sum;
        #pragma unroll
        for (int r = 0; r < 4; ++r) { p0[r] *= inv; p1[r] *= inv; }

        if (w == 0) {
            #pragma unroll
            for (int r = 0; r < 4; ++r) {
                const int j0 = 4 * q + r;
                if ((unsigned)(j0 - t) < 16u)
                    p_out[(rowbase + t) * 16 + (j0 - t)] = p0[r];
                else
                    p_out[(rowbase + t) * 16 + (j0 + 16 - t)] = p1[r];
            }
        }
        pf.u[0] = pack_bf2(p0[0], p0[1]); pf.u[1] = pack_bf2(p0[2], p0[3]);
        pf.u[2] = pack_bf2(p1[0], p1[1]); pf.u[3] = pack_bf2(p1[2], p1[3]);
    }

    // ---- phase B: MFMA from prefetched C fragments (no LDS) ----
    #pragma unroll
    for (int m = 0; m < 4; ++m) {
        f32x4 o = {0.f, 0.f, 0.f, 0.f};
        o = __builtin_amdgcn_mfma_f32_16x16x32_bf16(afc[m].v, pf.v, o, 0, 0, 0);
        float* ob = out + (rowbase + t) * 1024 + (w * 4 + m) * 16 + 4 * q;
        *(float4*)ob = make_float4(o[0], o[1], o[2], o[3]);
    }
}

extern "C" void kernel_launch(void* const* d_in, const int* in_sizes, int n_in,
                              void* d_out, int out_size, void* d_ws, size_t ws_size,
                              hipStream_t stream) {
    const int*   symbols   = (const int*)d_in[0];
    const float* encodings = (const float*)d_in[1];
    const float* M         = (const float*)d_in[2];
    const float* C         = (const float*)d_in[3];
    float* out   = (float*)d_out;
    float* p_out = out + (size_t)B_ * T_ * 1024;   // concat order: output, then p

    dim3 grid(B_ * (T_ / 16));                     // 1024 blocks x 512 threads
    attn_cell_kernel<<<grid, 512, 0, stream>>>(symbols, encodings, M, C, out, p_out);
}